// Round 1
// baseline (193.903 us; speedup 1.0000x reference)
//
#include <hip/hip_runtime.h>
#include <cmath>

#define NCLS 80

// cells per level: 32*3*g*g for g in {52,26,13}
#define CELL0 259584
#define CELL1 64896
#define CELL2 16224
#define CELLT (CELL0 + CELL1 + CELL2)

// ws float layout: [0..2]=lbox_sum  [3..5]=cls_sum  [6..8]=nvalid  [9..11]=lobj_sum  [16..16+CELLT)=tobj
#define TOBJ_OFF 16

__device__ __constant__ float c_anch[3][3][2] = {
    {{1.25f, 1.625f}, {2.0f, 3.75f}, {4.125f, 2.875f}},
    {{1.875f, 3.8125f}, {3.875f, 2.8125f}, {3.6875f, 7.4375f}},
    {{3.625f, 2.8125f}, {4.875f, 6.1875f}, {11.65625f, 10.1875f}}};
__device__ __constant__ float c_offx[5] = {0.f, 0.5f, 0.f, -0.5f, 0.f};
__device__ __constant__ float c_offy[5] = {0.f, 0.f, 0.5f, 0.f, -0.5f};

__device__ __forceinline__ float bce(float x, float y) {
    return fmaxf(x, 0.f) - x * y + log1pf(expf(-fabsf(x)));
}

// One 64-lane wave per entry; 4 waves (4 entries) per block. 23040 entries -> 5760 blocks.
__global__ __launch_bounds__(256) void k_targets(const float* __restrict__ p0,
                                                 const float* __restrict__ p1,
                                                 const float* __restrict__ p2,
                                                 const float* __restrict__ tgt,
                                                 float* __restrict__ ws) {
    const int lane = threadIdx.x & 63;
    const int wid = threadIdx.x >> 6;
    const int gid = blockIdx.x * 4 + wid;  // entry index 0..23039
    const int lev = gid / 7680;
    const int m = gid - lev * 7680;
    const int o = m / 1536;
    const int n = m - o * 1536;
    const int a = n >> 9;   // anchor 0..2
    const int j = n & 511;  // target 0..511

    const int gsz = (lev == 0) ? 52 : ((lev == 1) ? 26 : 13);
    const float* p = (lev == 0) ? p0 : ((lev == 1) ? p1 : p2);
    const int toff = (lev == 0) ? 0 : ((lev == 1) ? CELL0 : (CELL0 + CELL1));

    // target row (broadcast loads, all lanes same address)
    const float img = tgt[j * 6 + 0];
    const float cls = tgt[j * 6 + 1];
    const float x1 = tgt[j * 6 + 2], y1 = tgt[j * 6 + 3];
    const float x2 = tgt[j * 6 + 4], y2 = tgt[j * 6 + 5];
    const float w = (float)gsz, h = (float)gsz;
    const float cx = (x1 + x2) * 0.5f, cy = (y1 + y2) * 0.5f;
    const float tw = x2 - x1, th = y2 - y1;
    const float gx = cx * w, gy = cy * h, gw = tw * w, gh = th * h;

    // anchor-ratio mask
    const float ax = c_anch[lev][a][0], ay = c_anch[lev][a][1];
    const float rx = gw / ax, ry = gh / ay;
    const float mr = fmaxf(fmaxf(rx, 1.0f / rx), fmaxf(ry, 1.0f / ry));
    bool valid = (mr < 4.0f);
    if (o == 1)
        valid = valid && (fmodf(gx, 1.0f) < 0.5f) && (gx > 1.0f);
    else if (o == 2)
        valid = valid && (fmodf(gy, 1.0f) < 0.5f) && (gy > 1.0f);
    else if (o == 3) {
        const float gxi = w - gx;
        valid = valid && (fmodf(gxi, 1.0f) < 0.5f) && (gxi > 1.0f);
    } else if (o == 4) {
        const float gyi = h - gy;
        valid = valid && (fmodf(gyi, 1.0f) < 0.5f) && (gyi > 1.0f);
    }

    float lbox_part = 0.f, cls_part = 0.f, cnt = 0.f;

    if (valid) {
        const float gijx = floorf(gx - c_offx[o]);
        const float gijy = floorf(gy - c_offy[o]);
        int gi = (int)gijx;
        gi = min(max(gi, 0), gsz - 1);
        int gj = (int)gijy;
        gj = min(max(gj, 0), gsz - 1);
        const int b = (int)img;
        const int c = (int)cls;
        const int cell = ((b * 3 + a) * gsz + gj) * gsz + gi;
        const long base = (long)cell * 85;

        // coalesced row gather: lane i -> elem i; lanes 0..20 also elem 64+i
        const float xA = p[base + lane];
        const float xB = (lane < 21) ? p[base + 64 + lane] : 0.f;

        const float t0 = __shfl(xA, 0);
        const float t1 = __shfl(xA, 1);
        const float t2 = __shfl(xA, 2);
        const float t3 = __shfl(xA, 3);

        const float sx = 1.f / (1.f + expf(-t0));
        const float sy = 1.f / (1.f + expf(-t1));
        const float sw = 1.f / (1.f + expf(-t2));
        const float sh = 1.f / (1.f + expf(-t3));
        const float pxc = sx * 2.f - 0.5f;
        const float pyc = sy * 2.f - 0.5f;
        const float pw = (sw * 2.f) * (sw * 2.f) * ax;
        const float ph = (sh * 2.f) * (sh * 2.f) * ay;

        const float tbx = gx - gijx, tby = gy - gijy, tbw = gw, tbh = gh;

        // CIoU(box1=[pxc,pyc,pw,ph], box2=[tbx,tby,tbw,tbh])
        const float b1x1 = pxc - pw * 0.5f, b1x2 = pxc + pw * 0.5f;
        const float b1y1 = pyc - ph * 0.5f, b1y2 = pyc + ph * 0.5f;
        const float b2x1 = tbx - tbw * 0.5f, b2x2 = tbx + tbw * 0.5f;
        const float b2y1 = tby - tbh * 0.5f, b2y2 = tby + tbh * 0.5f;
        float iw = fminf(b1x2, b2x2) - fmaxf(b1x1, b2x1);
        iw = fmaxf(iw, 0.f);
        float ih = fminf(b1y2, b2y2) - fmaxf(b1y1, b2y1);
        ih = fmaxf(ih, 0.f);
        const float inter = iw * ih;
        const float uni = pw * ph + tbw * tbh - inter + 1e-7f;
        const float iou = inter / uni;
        const float cw = fmaxf(b1x2, b2x2) - fminf(b1x1, b2x1);
        const float ch = fmaxf(b1y2, b2y2) - fminf(b1y1, b2y1);
        const float c2 = cw * cw + ch * ch + 1e-7f;
        const float dx = b2x1 + b2x2 - b1x1 - b1x2;
        const float dy = b2y1 + b2y2 - b1y1 - b1y2;
        const float rho2 = (dx * dx + dy * dy) * 0.25f;
        const float dv = atanf(tbw / tbh) - atanf(pw / ph);
        const float v = 0.40528473f * dv * dv;  // 4/pi^2
        const float alpha = v / (v - iou + 1.0000001f);
        const float ciou = iou - (rho2 / c2 + v * alpha);

        lbox_part = 1.f - ciou;
        const float score = fmaxf(ciou, 0.f);
        cnt = 1.f;

        // class BCE: classes 0..58 from xA lanes 5..63, classes 59..79 from xB lanes 0..20
        float s = 0.f;
        if (lane >= 5) {
            const int k = lane - 5;
            s += bce(xA, (k == c) ? 0.95f : 0.05f);
        }
        if (lane < 21) {
            const int k = 59 + lane;
            s += bce(xB, (k == c) ? 0.95f : 0.05f);
        }
        for (int msk = 32; msk; msk >>= 1) s += __shfl_xor(s, msk);
        cls_part = s;

        // scatter-max score into tobj (non-negative floats: uint order == float order)
        if (lane == 0 && score > 0.f) {
            unsigned int* tobj = (unsigned int*)(ws + TOBJ_OFF + toff);
            atomicMax(tobj + cell, __float_as_uint(score));
        }
    }

    // block reduce (4 waves, all in same level since 7680 % 4 == 0)
    __shared__ float sb[4], sc[4], sn[4];
    if (lane == 0) {
        sb[wid] = lbox_part;
        sc[wid] = cls_part;
        sn[wid] = cnt;
    }
    __syncthreads();
    if (threadIdx.x == 0) {
        const float B = sb[0] + sb[1] + sb[2] + sb[3];
        const float C = sc[0] + sc[1] + sc[2] + sc[3];
        const float N = sn[0] + sn[1] + sn[2] + sn[3];
        if (N != 0.f) {
            atomicAdd(&ws[lev], B);
            atomicAdd(&ws[3 + lev], C);
            atomicAdd(&ws[6 + lev], N);
        }
    }
}

// One thread per cell: strided read of obj channel + coalesced tobj, bce, 3-way reduce.
__global__ __launch_bounds__(256) void k_obj(const float* __restrict__ p0,
                                             const float* __restrict__ p1,
                                             const float* __restrict__ p2,
                                             float* __restrict__ ws) {
    const int idx = blockIdx.x * 256 + threadIdx.x;
    float v0 = 0.f, v1 = 0.f, v2 = 0.f;
    if (idx < CELLT) {
        const float* p;
        int cell, toff, lev;
        if (idx < CELL0) {
            lev = 0; cell = idx; p = p0; toff = 0;
        } else if (idx < CELL0 + CELL1) {
            lev = 1; cell = idx - CELL0; p = p1; toff = CELL0;
        } else {
            lev = 2; cell = idx - (CELL0 + CELL1); p = p2; toff = CELL0 + CELL1;
        }
        const float x = p[(long)cell * 85 + 4];
        const float t = ws[TOBJ_OFF + toff + cell];
        const float b = fmaxf(x, 0.f) - x * t + log1pf(expf(-fabsf(x)));
        if (lev == 0) v0 = b;
        else if (lev == 1) v1 = b;
        else v2 = b;
    }
    for (int msk = 32; msk; msk >>= 1) {
        v0 += __shfl_xor(v0, msk);
        v1 += __shfl_xor(v1, msk);
        v2 += __shfl_xor(v2, msk);
    }
    __shared__ float s0[4], s1[4], s2[4];
    const int wid = threadIdx.x >> 6, lane = threadIdx.x & 63;
    if (lane == 0) {
        s0[wid] = v0;
        s1[wid] = v1;
        s2[wid] = v2;
    }
    __syncthreads();
    if (threadIdx.x == 0) {
        const float a0 = s0[0] + s0[1] + s0[2] + s0[3];
        const float a1 = s1[0] + s1[1] + s1[2] + s1[3];
        const float a2 = s2[0] + s2[1] + s2[2] + s2[3];
        if (a0 != 0.f) atomicAdd(&ws[9], a0);
        if (a1 != 0.f) atomicAdd(&ws[10], a1);
        if (a2 != 0.f) atomicAdd(&ws[11], a2);
    }
}

__global__ void k_final(const float* __restrict__ ws, float* __restrict__ out) {
    float lbox = 0.f, lobj = 0.f, lcls = 0.f;
    const float bal[3] = {4.0f, 1.0f, 0.4f};
    const float ncell[3] = {(float)CELL0, (float)CELL1, (float)CELL2};
    for (int l = 0; l < 3; ++l) {
        const float nv = fmaxf(ws[6 + l], 1.0f);
        lbox += ws[l] / nv;
        lcls += ws[3 + l] / (nv * (float)NCLS);
        lobj += ws[9 + l] / ncell[l] * bal[l];
    }
    lbox *= 0.05f;
    lcls *= 0.5f;
    const float total = (lbox + lobj + lcls) * 32.0f;
    out[0] = total;
    out[1] = lbox;
    out[2] = lobj;
    out[3] = lcls;
}

extern "C" void kernel_launch(void* const* d_in, const int* in_sizes, int n_in,
                              void* d_out, int out_size, void* d_ws, size_t ws_size,
                              hipStream_t stream) {
    const float* p0 = (const float*)d_in[0];
    const float* p1 = (const float*)d_in[1];
    const float* p2 = (const float*)d_in[2];
    const float* tgt = (const float*)d_in[3];
    float* ws = (float*)d_ws;
    float* out = (float*)d_out;

    hipMemsetAsync(d_ws, 0, (size_t)(TOBJ_OFF + CELLT) * sizeof(float), stream);
    k_targets<<<5760, 256, 0, stream>>>(p0, p1, p2, tgt, ws);
    k_obj<<<(CELLT + 255) / 256, 256, 0, stream>>>(p0, p1, p2, ws);
    k_final<<<1, 1, 0, stream>>>(ws, out);
}

// Round 2
// 48.169 us; speedup vs baseline: 4.0255x; 4.0255x over previous
//
#include <hip/hip_runtime.h>
#include <cmath>

#define NCLS 80

// cells per level: 32*3*g*g for g in {52,26,13}
#define CELL0 259584
#define CELL1 64896
#define CELL2 16224
#define CELLT (CELL0 + CELL1 + CELL2)

#define NTGT_BLOCKS 5760                    // 23040 entries / 4 waves per block
#define NOBJ_BLOCKS ((CELLT + 255) / 256)   // 1331

// ws float layout:
//  [TOBJ_OFF .. TOBJ_OFF+CELLT)                  tobj (zeroed each call)
//  [PART_OFF .. PART_OFF+NTGT_BLOCKS*4)          per-block {lbox, cls, nvalid, pad}
//  [OPART_OFF .. OPART_OFF+NOBJ_BLOCKS*4)        per-block {obj0, obj1, obj2, pad}
#define TOBJ_OFF 16
#define PART_OFF (TOBJ_OFF + CELLT)
#define OPART_OFF (PART_OFF + NTGT_BLOCKS * 4)

__device__ __constant__ float c_anch[3][3][2] = {
    {{1.25f, 1.625f}, {2.0f, 3.75f}, {4.125f, 2.875f}},
    {{1.875f, 3.8125f}, {3.875f, 2.8125f}, {3.6875f, 7.4375f}},
    {{3.625f, 2.8125f}, {4.875f, 6.1875f}, {11.65625f, 10.1875f}}};
__device__ __constant__ float c_offx[5] = {0.f, 0.5f, 0.f, -0.5f, 0.f};
__device__ __constant__ float c_offy[5] = {0.f, 0.f, 0.5f, 0.f, -0.5f};

__device__ __forceinline__ float bce(float x, float y) {
    return fmaxf(x, 0.f) - x * y + log1pf(expf(-fabsf(x)));
}

// One 64-lane wave per entry; 4 waves (4 entries) per block. 23040 entries -> 5760 blocks.
// NO global atomics for the sums: per-block partials written to private slots.
__global__ __launch_bounds__(256) void k_targets(const float* __restrict__ p0,
                                                 const float* __restrict__ p1,
                                                 const float* __restrict__ p2,
                                                 const float* __restrict__ tgt,
                                                 float* __restrict__ ws) {
    const int lane = threadIdx.x & 63;
    const int wid = threadIdx.x >> 6;
    const int gid = blockIdx.x * 4 + wid;  // entry index 0..23039
    const int lev = gid / 7680;
    const int m = gid - lev * 7680;
    const int o = m / 1536;
    const int n = m - o * 1536;
    const int a = n >> 9;   // anchor 0..2
    const int j = n & 511;  // target 0..511

    const int gsz = (lev == 0) ? 52 : ((lev == 1) ? 26 : 13);
    const float* p = (lev == 0) ? p0 : ((lev == 1) ? p1 : p2);
    const int toff = (lev == 0) ? 0 : ((lev == 1) ? CELL0 : (CELL0 + CELL1));

    // target row (vector broadcast loads)
    const float2 t01 = *(const float2*)(tgt + j * 6 + 0);
    const float2 t23 = *(const float2*)(tgt + j * 6 + 2);
    const float2 t45 = *(const float2*)(tgt + j * 6 + 4);
    const float img = t01.x, cls = t01.y;
    const float x1 = t23.x, y1 = t23.y, x2 = t45.x, y2 = t45.y;
    const float w = (float)gsz, h = (float)gsz;
    const float cx = (x1 + x2) * 0.5f, cy = (y1 + y2) * 0.5f;
    const float tw = x2 - x1, th = y2 - y1;
    const float gx = cx * w, gy = cy * h, gw = tw * w, gh = th * h;

    // anchor-ratio mask
    const float ax = c_anch[lev][a][0], ay = c_anch[lev][a][1];
    const float rx = gw / ax, ry = gh / ay;
    const float mr = fmaxf(fmaxf(rx, 1.0f / rx), fmaxf(ry, 1.0f / ry));
    bool valid = (mr < 4.0f);
    // gx, gy in (0, w) so mod 1.0 == x - floor(x)
    if (o == 1)
        valid = valid && (gx - floorf(gx) < 0.5f) && (gx > 1.0f);
    else if (o == 2)
        valid = valid && (gy - floorf(gy) < 0.5f) && (gy > 1.0f);
    else if (o == 3) {
        const float gxi = w - gx;
        valid = valid && (gxi - floorf(gxi) < 0.5f) && (gxi > 1.0f);
    } else if (o == 4) {
        const float gyi = h - gy;
        valid = valid && (gyi - floorf(gyi) < 0.5f) && (gyi > 1.0f);
    }

    float lbox_part = 0.f, cls_part = 0.f, cnt = 0.f;

    if (valid) {
        const float gijx = floorf(gx - c_offx[o]);
        const float gijy = floorf(gy - c_offy[o]);
        int gi = (int)gijx;
        gi = min(max(gi, 0), gsz - 1);
        int gj = (int)gijy;
        gj = min(max(gj, 0), gsz - 1);
        const int b = (int)img;
        const int c = (int)cls;
        const int cell = ((b * 3 + a) * gsz + gj) * gsz + gi;
        const long base = (long)cell * 85;

        // coalesced row gather: lane i -> elem i; lanes 0..20 also elem 64+i
        const float xA = p[base + lane];
        const float xB = (lane < 21) ? p[base + 64 + lane] : 0.f;

        const float t0 = __shfl(xA, 0);
        const float t1 = __shfl(xA, 1);
        const float t2 = __shfl(xA, 2);
        const float t3 = __shfl(xA, 3);

        const float sx = 1.f / (1.f + expf(-t0));
        const float sy = 1.f / (1.f + expf(-t1));
        const float sw = 1.f / (1.f + expf(-t2));
        const float sh = 1.f / (1.f + expf(-t3));
        const float pxc = sx * 2.f - 0.5f;
        const float pyc = sy * 2.f - 0.5f;
        const float pw = (sw * 2.f) * (sw * 2.f) * ax;
        const float ph = (sh * 2.f) * (sh * 2.f) * ay;

        const float tbx = gx - gijx, tby = gy - gijy, tbw = gw, tbh = gh;

        // CIoU(box1=[pxc,pyc,pw,ph], box2=[tbx,tby,tbw,tbh])
        const float b1x1 = pxc - pw * 0.5f, b1x2 = pxc + pw * 0.5f;
        const float b1y1 = pyc - ph * 0.5f, b1y2 = pyc + ph * 0.5f;
        const float b2x1 = tbx - tbw * 0.5f, b2x2 = tbx + tbw * 0.5f;
        const float b2y1 = tby - tbh * 0.5f, b2y2 = tby + tbh * 0.5f;
        float iw = fminf(b1x2, b2x2) - fmaxf(b1x1, b2x1);
        iw = fmaxf(iw, 0.f);
        float ih = fminf(b1y2, b2y2) - fmaxf(b1y1, b2y1);
        ih = fmaxf(ih, 0.f);
        const float inter = iw * ih;
        const float uni = pw * ph + tbw * tbh - inter + 1e-7f;
        const float iou = inter / uni;
        const float cw = fmaxf(b1x2, b2x2) - fminf(b1x1, b2x1);
        const float ch = fmaxf(b1y2, b2y2) - fminf(b1y1, b2y1);
        const float c2 = cw * cw + ch * ch + 1e-7f;
        const float dx = b2x1 + b2x2 - b1x1 - b1x2;
        const float dy = b2y1 + b2y2 - b1y1 - b1y2;
        const float rho2 = (dx * dx + dy * dy) * 0.25f;
        const float dv = atanf(tbw / tbh) - atanf(pw / ph);
        const float v = 0.40528473f * dv * dv;  // 4/pi^2
        const float alpha = v / (v - iou + 1.0000001f);
        const float ciou = iou - (rho2 / c2 + v * alpha);

        lbox_part = 1.f - ciou;
        const float score = fmaxf(ciou, 0.f);
        cnt = 1.f;

        // class BCE: classes 0..58 from xA lanes 5..63, classes 59..79 from xB lanes 0..20
        float s = 0.f;
        if (lane >= 5) {
            const int k = lane - 5;
            s += bce(xA, (k == c) ? 0.95f : 0.05f);
        }
        if (lane < 21) {
            const int k = 59 + lane;
            s += bce(xB, (k == c) ? 0.95f : 0.05f);
        }
        for (int msk = 32; msk; msk >>= 1) s += __shfl_xor(s, msk);
        cls_part = s;

        // scatter-max score into tobj (non-negative floats: uint order == float order).
        // Scattered addresses -> no meaningful contention.
        if (lane == 0 && score > 0.f) {
            unsigned int* tobj = (unsigned int*)(ws + TOBJ_OFF + toff);
            atomicMax(tobj + cell, __float_as_uint(score));
        }
    }

    // block reduce (4 waves, all same level since 7680 % 4 == 0) -> private slot, NO atomics
    __shared__ float sb[4], sc[4], sn[4];
    if (lane == 0) {
        sb[wid] = lbox_part;
        sc[wid] = cls_part;
        sn[wid] = cnt;
    }
    __syncthreads();
    if (threadIdx.x == 0) {
        float* slot = ws + PART_OFF + blockIdx.x * 4;
        slot[0] = sb[0] + sb[1] + sb[2] + sb[3];
        slot[1] = sc[0] + sc[1] + sc[2] + sc[3];
        slot[2] = sn[0] + sn[1] + sn[2] + sn[3];
    }
}

// One thread per cell: strided read of obj channel + coalesced tobj, bce, per-block partials.
__global__ __launch_bounds__(256) void k_obj(const float* __restrict__ p0,
                                             const float* __restrict__ p1,
                                             const float* __restrict__ p2,
                                             float* __restrict__ ws) {
    const int idx = blockIdx.x * 256 + threadIdx.x;
    float v0 = 0.f, v1 = 0.f, v2 = 0.f;
    if (idx < CELLT) {
        const float* p;
        int cell, toff, lev;
        if (idx < CELL0) {
            lev = 0; cell = idx; p = p0; toff = 0;
        } else if (idx < CELL0 + CELL1) {
            lev = 1; cell = idx - CELL0; p = p1; toff = CELL0;
        } else {
            lev = 2; cell = idx - (CELL0 + CELL1); p = p2; toff = CELL0 + CELL1;
        }
        const float x = p[(long)cell * 85 + 4];
        const float t = ws[TOBJ_OFF + toff + cell];
        const float b = fmaxf(x, 0.f) - x * t + log1pf(expf(-fabsf(x)));
        if (lev == 0) v0 = b;
        else if (lev == 1) v1 = b;
        else v2 = b;
    }
    for (int msk = 32; msk; msk >>= 1) {
        v0 += __shfl_xor(v0, msk);
        v1 += __shfl_xor(v1, msk);
        v2 += __shfl_xor(v2, msk);
    }
    __shared__ float s0[4], s1[4], s2[4];
    const int wid = threadIdx.x >> 6, lane = threadIdx.x & 63;
    if (lane == 0) {
        s0[wid] = v0;
        s1[wid] = v1;
        s2[wid] = v2;
    }
    __syncthreads();
    if (threadIdx.x == 0) {
        float* slot = ws + OPART_OFF + blockIdx.x * 4;
        slot[0] = s0[0] + s0[1] + s0[2] + s0[3];
        slot[1] = s1[0] + s1[1] + s1[2] + s1[3];
        slot[2] = s2[0] + s2[1] + s2[2] + s2[3];
    }
}

// Single 256-thread block: deterministic reduction of all partials + final combine.
__global__ __launch_bounds__(256) void k_final(const float* __restrict__ ws,
                                               float* __restrict__ out) {
    // acc[0..2]=lbox per level, [3..5]=cls, [6..8]=nvalid, [9..11]=obj
    float acc[12];
#pragma unroll
    for (int q = 0; q < 12; ++q) acc[q] = 0.f;

    for (int i = threadIdx.x; i < NTGT_BLOCKS; i += 256) {
        const int lev = i / 1920;  // k_targets blocks 0..1919 -> lev0, etc.
        const float* slot = ws + PART_OFF + i * 4;
        acc[lev] += slot[0];
        acc[3 + lev] += slot[1];
        acc[6 + lev] += slot[2];
    }
    for (int i = threadIdx.x; i < NOBJ_BLOCKS; i += 256) {
        const float* slot = ws + OPART_OFF + i * 4;
        acc[9] += slot[0];
        acc[10] += slot[1];
        acc[11] += slot[2];
    }
#pragma unroll
    for (int q = 0; q < 12; ++q)
        for (int msk = 32; msk; msk >>= 1) acc[q] += __shfl_xor(acc[q], msk);

    __shared__ float sh[4][12];
    const int wid = threadIdx.x >> 6, lane = threadIdx.x & 63;
    if (lane == 0)
#pragma unroll
        for (int q = 0; q < 12; ++q) sh[wid][q] = acc[q];
    __syncthreads();

    if (threadIdx.x == 0) {
        float lbox = 0.f, lobj = 0.f, lcls = 0.f;
        const float bal[3] = {4.0f, 1.0f, 0.4f};
        const float ncell[3] = {(float)CELL0, (float)CELL1, (float)CELL2};
        for (int l = 0; l < 3; ++l) {
            const float sb = sh[0][l] + sh[1][l] + sh[2][l] + sh[3][l];
            const float sc = sh[0][3 + l] + sh[1][3 + l] + sh[2][3 + l] + sh[3][3 + l];
            const float sn = sh[0][6 + l] + sh[1][6 + l] + sh[2][6 + l] + sh[3][6 + l];
            const float so = sh[0][9 + l] + sh[1][9 + l] + sh[2][9 + l] + sh[3][9 + l];
            const float nv = fmaxf(sn, 1.0f);
            lbox += sb / nv;
            lcls += sc / (nv * (float)NCLS);
            lobj += so / ncell[l] * bal[l];
        }
        lbox *= 0.05f;
        lcls *= 0.5f;
        const float total = (lbox + lobj + lcls) * 32.0f;
        out[0] = total;
        out[1] = lbox;
        out[2] = lobj;
        out[3] = lcls;
    }
}

extern "C" void kernel_launch(void* const* d_in, const int* in_sizes, int n_in,
                              void* d_out, int out_size, void* d_ws, size_t ws_size,
                              hipStream_t stream) {
    const float* p0 = (const float*)d_in[0];
    const float* p1 = (const float*)d_in[1];
    const float* p2 = (const float*)d_in[2];
    const float* tgt = (const float*)d_in[3];
    float* ws = (float*)d_ws;
    float* out = (float*)d_out;

    // zero only the tobj region (+ header); partial slots are written unconditionally
    hipMemsetAsync(d_ws, 0, (size_t)(TOBJ_OFF + CELLT) * sizeof(float), stream);
    k_targets<<<NTGT_BLOCKS, 256, 0, stream>>>(p0, p1, p2, tgt, ws);
    k_obj<<<NOBJ_BLOCKS, 256, 0, stream>>>(p0, p1, p2, ws);
    k_final<<<1, 256, 0, stream>>>(ws, out);
}

// Round 3
// 47.714 us; speedup vs baseline: 4.0639x; 1.0095x over previous
//
#include <hip/hip_runtime.h>
#include <cmath>

#define NCLS 80

// cells per level: 32*3*g*g for g in {52,26,13}
#define CELL0 259584
#define CELL1 64896
#define CELL2 16224
#define CELLT (CELL0 + CELL1 + CELL2)

#define NTGT_BLOCKS 5760                    // 23040 entries / 4 waves per block
#define NOBJ_BLOCKS ((CELLT + 255) / 256)   // 1331

// ws float layout:
//  [TOBJ_OFF .. TOBJ_OFF+CELLT)                  tobj (zeroed each call by k_zero)
//  [PART_OFF .. PART_OFF+NTGT_BLOCKS*4)          per-block {lbox, cls, nvalid, pad}
//  [OPART_OFF .. OPART_OFF+NOBJ_BLOCKS*4)        per-block {obj0, obj1, obj2, pad}
#define TOBJ_OFF 16
#define PART_OFF (TOBJ_OFF + CELLT)
#define OPART_OFF (PART_OFF + NTGT_BLOCKS * 4)

#define ZERO_F4 (CELLT / 4)                 // 85176, CELLT % 4 == 0
#define NZERO_BLOCKS ((ZERO_F4 + 255) / 256)

__device__ __constant__ float c_anch[3][3][2] = {
    {{1.25f, 1.625f}, {2.0f, 3.75f}, {4.125f, 2.875f}},
    {{1.875f, 3.8125f}, {3.875f, 2.8125f}, {3.6875f, 7.4375f}},
    {{3.625f, 2.8125f}, {4.875f, 6.1875f}, {11.65625f, 10.1875f}}};
__device__ __constant__ float c_offx[5] = {0.f, 0.5f, 0.f, -0.5f, 0.f};
__device__ __constant__ float c_offy[5] = {0.f, 0.f, 0.5f, 0.f, -0.5f};

__device__ __forceinline__ float bce(float x, float y) {
    return fmaxf(x, 0.f) - x * y + log1pf(expf(-fabsf(x)));
}

// Vectorized zero of the tobj region (the rocclr fill kernel took ~52 us for this).
__global__ __launch_bounds__(256) void k_zero(float* __restrict__ ws) {
    const int i = blockIdx.x * 256 + threadIdx.x;
    if (i < ZERO_F4) {
        float4 z;
        z.x = 0.f; z.y = 0.f; z.z = 0.f; z.w = 0.f;
        ((float4*)(ws + TOBJ_OFF))[i] = z;
    }
}

// One 64-lane wave per entry; 4 waves (4 entries) per block. 23040 entries -> 5760 blocks.
// NO global atomics for the sums: per-block partials written to private slots.
__global__ __launch_bounds__(256) void k_targets(const float* __restrict__ p0,
                                                 const float* __restrict__ p1,
                                                 const float* __restrict__ p2,
                                                 const float* __restrict__ tgt,
                                                 float* __restrict__ ws) {
    const int lane = threadIdx.x & 63;
    const int wid = threadIdx.x >> 6;
    const int gid = blockIdx.x * 4 + wid;  // entry index 0..23039
    const int lev = gid / 7680;
    const int m = gid - lev * 7680;
    const int o = m / 1536;
    const int n = m - o * 1536;
    const int a = n >> 9;   // anchor 0..2
    const int j = n & 511;  // target 0..511

    const int gsz = (lev == 0) ? 52 : ((lev == 1) ? 26 : 13);
    const float* p = (lev == 0) ? p0 : ((lev == 1) ? p1 : p2);
    const int toff = (lev == 0) ? 0 : ((lev == 1) ? CELL0 : (CELL0 + CELL1));

    // target row (vector broadcast loads)
    const float2 t01 = *(const float2*)(tgt + j * 6 + 0);
    const float2 t23 = *(const float2*)(tgt + j * 6 + 2);
    const float2 t45 = *(const float2*)(tgt + j * 6 + 4);
    const float img = t01.x, cls = t01.y;
    const float x1 = t23.x, y1 = t23.y, x2 = t45.x, y2 = t45.y;
    const float w = (float)gsz, h = (float)gsz;
    const float cx = (x1 + x2) * 0.5f, cy = (y1 + y2) * 0.5f;
    const float tw = x2 - x1, th = y2 - y1;
    const float gx = cx * w, gy = cy * h, gw = tw * w, gh = th * h;

    // anchor-ratio mask
    const float ax = c_anch[lev][a][0], ay = c_anch[lev][a][1];
    const float rx = gw / ax, ry = gh / ay;
    const float mr = fmaxf(fmaxf(rx, 1.0f / rx), fmaxf(ry, 1.0f / ry));
    bool valid = (mr < 4.0f);
    // gx, gy in (0, w) so mod 1.0 == x - floor(x)
    if (o == 1)
        valid = valid && (gx - floorf(gx) < 0.5f) && (gx > 1.0f);
    else if (o == 2)
        valid = valid && (gy - floorf(gy) < 0.5f) && (gy > 1.0f);
    else if (o == 3) {
        const float gxi = w - gx;
        valid = valid && (gxi - floorf(gxi) < 0.5f) && (gxi > 1.0f);
    } else if (o == 4) {
        const float gyi = h - gy;
        valid = valid && (gyi - floorf(gyi) < 0.5f) && (gyi > 1.0f);
    }

    float lbox_part = 0.f, cls_part = 0.f, cnt = 0.f;

    if (valid) {
        const float gijx = floorf(gx - c_offx[o]);
        const float gijy = floorf(gy - c_offy[o]);
        int gi = (int)gijx;
        gi = min(max(gi, 0), gsz - 1);
        int gj = (int)gijy;
        gj = min(max(gj, 0), gsz - 1);
        const int b = (int)img;
        const int c = (int)cls;
        const int cell = ((b * 3 + a) * gsz + gj) * gsz + gi;
        const long base = (long)cell * 85;

        // coalesced row gather: lane i -> elem i; lanes 0..20 also elem 64+i
        const float xA = p[base + lane];
        const float xB = (lane < 21) ? p[base + 64 + lane] : 0.f;

        const float t0 = __shfl(xA, 0);
        const float t1 = __shfl(xA, 1);
        const float t2 = __shfl(xA, 2);
        const float t3 = __shfl(xA, 3);

        const float sx = 1.f / (1.f + expf(-t0));
        const float sy = 1.f / (1.f + expf(-t1));
        const float sw = 1.f / (1.f + expf(-t2));
        const float sh = 1.f / (1.f + expf(-t3));
        const float pxc = sx * 2.f - 0.5f;
        const float pyc = sy * 2.f - 0.5f;
        const float pw = (sw * 2.f) * (sw * 2.f) * ax;
        const float ph = (sh * 2.f) * (sh * 2.f) * ay;

        const float tbx = gx - gijx, tby = gy - gijy, tbw = gw, tbh = gh;

        // CIoU(box1=[pxc,pyc,pw,ph], box2=[tbx,tby,tbw,tbh])
        const float b1x1 = pxc - pw * 0.5f, b1x2 = pxc + pw * 0.5f;
        const float b1y1 = pyc - ph * 0.5f, b1y2 = pyc + ph * 0.5f;
        const float b2x1 = tbx - tbw * 0.5f, b2x2 = tbx + tbw * 0.5f;
        const float b2y1 = tby - tbh * 0.5f, b2y2 = tby + tbh * 0.5f;
        float iw = fminf(b1x2, b2x2) - fmaxf(b1x1, b2x1);
        iw = fmaxf(iw, 0.f);
        float ih = fminf(b1y2, b2y2) - fmaxf(b1y1, b2y1);
        ih = fmaxf(ih, 0.f);
        const float inter = iw * ih;
        const float uni = pw * ph + tbw * tbh - inter + 1e-7f;
        const float iou = inter / uni;
        const float cw = fmaxf(b1x2, b2x2) - fminf(b1x1, b2x1);
        const float ch = fmaxf(b1y2, b2y2) - fminf(b1y1, b2y1);
        const float c2 = cw * cw + ch * ch + 1e-7f;
        const float dx = b2x1 + b2x2 - b1x1 - b1x2;
        const float dy = b2y1 + b2y2 - b1y1 - b1y2;
        const float rho2 = (dx * dx + dy * dy) * 0.25f;
        const float dv = atanf(tbw / tbh) - atanf(pw / ph);
        const float v = 0.40528473f * dv * dv;  // 4/pi^2
        const float alpha = v / (v - iou + 1.0000001f);
        const float ciou = iou - (rho2 / c2 + v * alpha);

        lbox_part = 1.f - ciou;
        const float score = fmaxf(ciou, 0.f);
        cnt = 1.f;

        // class BCE: classes 0..58 from xA lanes 5..63, classes 59..79 from xB lanes 0..20
        float s = 0.f;
        if (lane >= 5) {
            const int k = lane - 5;
            s += bce(xA, (k == c) ? 0.95f : 0.05f);
        }
        if (lane < 21) {
            const int k = 59 + lane;
            s += bce(xB, (k == c) ? 0.95f : 0.05f);
        }
        for (int msk = 32; msk; msk >>= 1) s += __shfl_xor(s, msk);
        cls_part = s;

        // scatter-max score into tobj (non-negative floats: uint order == float order).
        // Scattered addresses -> no meaningful contention.
        if (lane == 0 && score > 0.f) {
            unsigned int* tobj = (unsigned int*)(ws + TOBJ_OFF + toff);
            atomicMax(tobj + cell, __float_as_uint(score));
        }
    }

    // block reduce (4 waves, all same level since 7680 % 4 == 0) -> private slot, NO atomics
    __shared__ float sb[4], sc[4], sn[4];
    if (lane == 0) {
        sb[wid] = lbox_part;
        sc[wid] = cls_part;
        sn[wid] = cnt;
    }
    __syncthreads();
    if (threadIdx.x == 0) {
        float* slot = ws + PART_OFF + blockIdx.x * 4;
        slot[0] = sb[0] + sb[1] + sb[2] + sb[3];
        slot[1] = sc[0] + sc[1] + sc[2] + sc[3];
        slot[2] = sn[0] + sn[1] + sn[2] + sn[3];
    }
}

// One thread per cell: strided read of obj channel + coalesced tobj, bce, per-block partials.
__global__ __launch_bounds__(256) void k_obj(const float* __restrict__ p0,
                                             const float* __restrict__ p1,
                                             const float* __restrict__ p2,
                                             float* __restrict__ ws) {
    const int idx = blockIdx.x * 256 + threadIdx.x;
    float v0 = 0.f, v1 = 0.f, v2 = 0.f;
    if (idx < CELLT) {
        const float* p;
        int cell, toff, lev;
        if (idx < CELL0) {
            lev = 0; cell = idx; p = p0; toff = 0;
        } else if (idx < CELL0 + CELL1) {
            lev = 1; cell = idx - CELL0; p = p1; toff = CELL0;
        } else {
            lev = 2; cell = idx - (CELL0 + CELL1); p = p2; toff = CELL0 + CELL1;
        }
        const float x = p[(long)cell * 85 + 4];
        const float t = ws[TOBJ_OFF + toff + cell];
        const float b = fmaxf(x, 0.f) - x * t + log1pf(expf(-fabsf(x)));
        if (lev == 0) v0 = b;
        else if (lev == 1) v1 = b;
        else v2 = b;
    }
    for (int msk = 32; msk; msk >>= 1) {
        v0 += __shfl_xor(v0, msk);
        v1 += __shfl_xor(v1, msk);
        v2 += __shfl_xor(v2, msk);
    }
    __shared__ float s0[4], s1[4], s2[4];
    const int wid = threadIdx.x >> 6, lane = threadIdx.x & 63;
    if (lane == 0) {
        s0[wid] = v0;
        s1[wid] = v1;
        s2[wid] = v2;
    }
    __syncthreads();
    if (threadIdx.x == 0) {
        float* slot = ws + OPART_OFF + blockIdx.x * 4;
        slot[0] = s0[0] + s0[1] + s0[2] + s0[3];
        slot[1] = s1[0] + s1[1] + s1[2] + s1[3];
        slot[2] = s2[0] + s2[1] + s2[2] + s2[3];
    }
}

// Single 256-thread block: deterministic reduction of all partials + final combine.
__global__ __launch_bounds__(256) void k_final(const float* __restrict__ ws,
                                               float* __restrict__ out) {
    // acc[0..2]=lbox per level, [3..5]=cls, [6..8]=nvalid, [9..11]=obj
    float acc[12];
#pragma unroll
    for (int q = 0; q < 12; ++q) acc[q] = 0.f;

    for (int i = threadIdx.x; i < NTGT_BLOCKS; i += 256) {
        const int lev = i / 1920;  // k_targets blocks 0..1919 -> lev0, etc.
        const float* slot = ws + PART_OFF + i * 4;
        acc[lev] += slot[0];
        acc[3 + lev] += slot[1];
        acc[6 + lev] += slot[2];
    }
    for (int i = threadIdx.x; i < NOBJ_BLOCKS; i += 256) {
        const float* slot = ws + OPART_OFF + i * 4;
        acc[9] += slot[0];
        acc[10] += slot[1];
        acc[11] += slot[2];
    }
#pragma unroll
    for (int q = 0; q < 12; ++q)
        for (int msk = 32; msk; msk >>= 1) acc[q] += __shfl_xor(acc[q], msk);

    __shared__ float sh[4][12];
    const int wid = threadIdx.x >> 6, lane = threadIdx.x & 63;
    if (lane == 0)
#pragma unroll
        for (int q = 0; q < 12; ++q) sh[wid][q] = acc[q];
    __syncthreads();

    if (threadIdx.x == 0) {
        float lbox = 0.f, lobj = 0.f, lcls = 0.f;
        const float bal[3] = {4.0f, 1.0f, 0.4f};
        const float ncell[3] = {(float)CELL0, (float)CELL1, (float)CELL2};
        for (int l = 0; l < 3; ++l) {
            const float sb = sh[0][l] + sh[1][l] + sh[2][l] + sh[3][l];
            const float sc = sh[0][3 + l] + sh[1][3 + l] + sh[2][3 + l] + sh[3][3 + l];
            const float sn = sh[0][6 + l] + sh[1][6 + l] + sh[2][6 + l] + sh[3][6 + l];
            const float so = sh[0][9 + l] + sh[1][9 + l] + sh[2][9 + l] + sh[3][9 + l];
            const float nv = fmaxf(sn, 1.0f);
            lbox += sb / nv;
            lcls += sc / (nv * (float)NCLS);
            lobj += so / ncell[l] * bal[l];
        }
        lbox *= 0.05f;
        lcls *= 0.5f;
        const float total = (lbox + lobj + lcls) * 32.0f;
        out[0] = total;
        out[1] = lbox;
        out[2] = lobj;
        out[3] = lcls;
    }
}

extern "C" void kernel_launch(void* const* d_in, const int* in_sizes, int n_in,
                              void* d_out, int out_size, void* d_ws, size_t ws_size,
                              hipStream_t stream) {
    const float* p0 = (const float*)d_in[0];
    const float* p1 = (const float*)d_in[1];
    const float* p2 = (const float*)d_in[2];
    const float* tgt = (const float*)d_in[3];
    float* ws = (float*)d_ws;
    float* out = (float*)d_out;

    k_zero<<<NZERO_BLOCKS, 256, 0, stream>>>(ws);
    k_targets<<<NTGT_BLOCKS, 256, 0, stream>>>(p0, p1, p2, tgt, ws);
    k_obj<<<NOBJ_BLOCKS, 256, 0, stream>>>(p0, p1, p2, ws);
    k_final<<<1, 256, 0, stream>>>(ws, out);
}